// Round 11
// baseline (131.483 us; speedup 1.0000x reference)
//
#include <hip/hip_runtime.h>
#include <hip/hip_bf16.h>

typedef short short8 __attribute__((ext_vector_type(8)));
typedef float f32x4 __attribute__((ext_vector_type(4)));
typedef unsigned int uint;

#define CB   16
#define TT   8
#define CIN  1024
#define ICH  512
#define HWS  196
#define NPB  1568   // cols per batch (196*8)
#define NF   25088  // flat cols = 16*1568

static __device__ __forceinline__ unsigned short f2bf(float f) {
  __hip_bfloat16 h = __float2bfloat16(f); unsigned short u; __builtin_memcpy(&u, &h, 2); return u;
}

// async global->LDS, 16B per lane; LDS dest is wave-uniform base + lane*16
static __device__ __forceinline__ void stage16(const void* g, void* l) {
  __builtin_amdgcn_global_load_lds(
      (const __attribute__((address_space(1))) unsigned int*)(unsigned long long)g,
      (__attribute__((address_space(3))) unsigned int*)(unsigned int)(unsigned long long)l,
      16, 0, 0);
}

// ---------------- fused prep: x-transpose blocks [0,8192) + weight blocks ----------------
__global__ void k_prep(const float* __restrict__ x, __hip_bfloat16* __restrict__ xbT,
    const float* __restrict__ w1, const float* __restrict__ w2,
    const float* __restrict__ wb1, const float* __restrict__ bb1,
    const float* __restrict__ wb2, const float* __restrict__ bb2,
    const float* __restrict__ wb3, const float* __restrict__ bb3,
    const float* __restrict__ wb4, const float* __restrict__ bb4,
    __hip_bfloat16* __restrict__ w1b, __hip_bfloat16* __restrict__ w2b,
    float* __restrict__ weff, float* __restrict__ beff) {
  int bid = blockIdx.x;
  if (bid >= CB * TT * 16 * 4) {
    int idx = (bid - CB * TT * 16 * 4) * 256 + threadIdx.x;
    if (idx < CIN * ICH) {
      w1b[idx] = __float2bfloat16(w1[idx]);
      w2b[idx] = __float2bfloat16(w2[idx]);
    }
    if (idx < ICH) {
      float e[7];
#pragma unroll
      for (int u = 0; u < 7; u++) e[u] = wb4[idx * 7 + u];
#pragma unroll
      for (int u = 0; u < 5; u++) e[u + 1] += wb3[idx * 5 + u];
#pragma unroll
      for (int u = 0; u < 3; u++) e[u + 2] += wb2[idx * 3 + u];
      e[3] += wb1[idx];
#pragma unroll
      for (int u = 0; u < 7; u++) weff[idx * 8 + u] = e[u];
      weff[idx * 8 + 7] = 0.f;
      beff[idx] = bb1[idx] + bb2[idx] + bb3[idx] + bb4[idx];
    }
    return;
  }
  __shared__ float tile[64][51];
  int ht = bid & 3;
  int ct = (bid >> 2) & 15;
  int t  = (bid >> 6) & 7;
  int b  = bid >> 9;
  int c0 = ct * 64, h0 = ht * 49;
  const float* src = x + ((size_t)((b * TT + t) * CIN + c0)) * HWS + h0;
  for (int idx = threadIdx.x; idx < 64 * 49; idx += 256) {
    int r = idx / 49, q = idx - r * 49;
    tile[r][q] = src[(size_t)r * HWS + q];
  }
  __syncthreads();
  for (int idx = threadIdx.x; idx < 49 * 16; idx += 256) {
    int h = idx >> 4, g = idx & 15;
    ushort4 pk;
    pk.x = f2bf(tile[g * 4 + 0][h]);
    pk.y = f2bf(tile[g * 4 + 1][h]);
    pk.z = f2bf(tile[g * 4 + 2][h]);
    pk.w = f2bf(tile[g * 4 + 3][h]);
    size_t n1 = (size_t)(h0 + h) * TT + t;
    *(ushort4*)&xbT[((size_t)b * NPB + n1) * CIN + (c0 + g * 4)] = pk;
  }
}

// ---------------- 256x256 GEMM core, BK=32, 3-buffer, end-of-iter single vmcnt+barrier ----------------
// 8 waves = 2m x 4n; A-frag mf -> rows mf*32 + wm*16 + ln; per-wave out 128x64, acc[8][4].
// LDS: 3 bufs x (A 16KB + B 16KB) = 96KB. 4 stage16 calls per tile (B h0, B h1, A h0, A h1).
// Iter t: read tile t (buf t%3) -- guaranteed landed+visible at END of iter t-1;
//         stage tile t+2 into buf (t+2)%3 (spread among the read issues);
//         two 16-MFMA clusters gated by lgkm(4)/lgkm(0);
//         end: vmcnt(4) drains tile t+1 (issued a FULL iter ago -> slack); s_barrier
//         gives (a) t+1 visibility (b) all reads of buf (t+3)%3==t%3 done before restage.
// FIFO: prologue 8 loads -> vmcnt(4) drains tile 0. Steady: 4(t+1)+4(t+2)=8 -> vmcnt(4).
// Tails: t=NT-2 vmcnt(0); t=NT-1 skip (epilogues re-sync LDS themselves).
// Swizzle: 64B rows, 4 slots; LDS slot s holds global chunk s ^ ((row>>1)&3); read slot
// = lm ^ ((ln>>1)&3) (uniform: row bases are multiples of 16) -> 2-way banks (free).
template <int KD>
static __device__ __forceinline__ void gemm_core32(
    const __hip_bfloat16* __restrict__ Ar,  // 256 rows x KD (k-contiguous)
    const __hip_bfloat16* __restrict__ Br,  // 256 rows x KD
    __hip_bfloat16* As, __hip_bfloat16* Bs, f32x4 (&acc)[8][4]) {
  constexpr int NT = KD / 32;
  const int tid = threadIdx.x;
  const int lane = tid & 63, w = tid >> 6;
  const int wm = w >> 2, wn = w & 3;
  const int ln = lane & 15, lm = lane >> 4;
  // staging: call(h) covers rows h*128 + w*16 + (lane>>2); slot lane&3; source chunk pre-swizzled
  const int srow = lane >> 2;                       // 0..15
  const int schk = (lane & 3) ^ ((lane >> 3) & 3);  // (lane&3) ^ ((srow>>1)&3)
  const __hip_bfloat16* aS = Ar + (size_t)(w * 16 + srow) * KD + schk * 8;
  const __hip_bfloat16* bS = Br + (size_t)(w * 16 + srow) * KD + schk * 8;
  __hip_bfloat16* aD = As + (w * 16) * 32;  // row stride 32 elems (64B); buf stride 8192 elems
  __hip_bfloat16* bD = Bs + (w * 16) * 32;
  const int slot = (lm ^ ((ln >> 1) & 3)) * 8;
  int ra[8], rb[4];
#pragma unroll
  for (int mf = 0; mf < 8; mf++) ra[mf] = (mf * 32 + wm * 16 + ln) * 32 + slot;
#pragma unroll
  for (int nf = 0; nf < 4; nf++) rb[nf] = (wn * 64 + nf * 16 + ln) * 32 + slot;

#define STG(src, dst, h, kt, buf) \
  stage16(src + (size_t)((h) * 128) * KD + (kt) * 32, dst + (buf) * 8192 + ((h) * 128) * 32)

  // prologue: tiles 0,1 -> bufs 0,1
  STG(bS, bD, 0, 0, 0); STG(bS, bD, 1, 0, 0); STG(aS, aD, 0, 0, 0); STG(aS, aD, 1, 0, 0);
  STG(bS, bD, 0, 1, 1); STG(bS, bD, 1, 1, 1); STG(aS, aD, 0, 1, 1); STG(aS, aD, 1, 1, 1);
  asm volatile("s_waitcnt vmcnt(4)" ::: "memory");  // tile 0 landed (tile 1 in flight)
  asm volatile("s_barrier" ::: "memory");

  short8 afA[4], afB[4], bf[4];
  for (int t = 0; t < NT; t++) {
    const int bc = t % 3;
    const bool has = (t + 2 < NT);
    const int nb = (t + 2) % 3;
    const __hip_bfloat16* Ab = As + bc * 8192;
    const __hip_bfloat16* Bb = Bs + bc * 8192;
    if (has) { STG(bS, bD, 0, t + 2, nb); STG(bS, bD, 1, t + 2, nb); }
#pragma unroll
    for (int q = 0; q < 4; q++) afA[q] = *(const short8*)&Ab[ra[q]];
#pragma unroll
    for (int nf = 0; nf < 4; nf++) bf[nf] = *(const short8*)&Bb[rb[nf]];
    __builtin_amdgcn_sched_barrier(0);  // pin: first 8 reads precede the next 4
    if (has) { STG(aS, aD, 0, t + 2, nb); STG(aS, aD, 1, t + 2, nb); }
#pragma unroll
    for (int q = 0; q < 4; q++) afB[q] = *(const short8*)&Ab[ra[4 + q]];
    asm volatile("s_waitcnt lgkmcnt(4)" ::: "memory");  // afA + bf done; afB in flight
    __builtin_amdgcn_sched_barrier(0);
    __builtin_amdgcn_s_setprio(1);
#pragma unroll
    for (int nf = 0; nf < 4; nf++)
#pragma unroll
      for (int q = 0; q < 4; q++)
        acc[q][nf] = __builtin_amdgcn_mfma_f32_16x16x32_bf16(afA[q], bf[nf], acc[q][nf], 0, 0, 0);
    __builtin_amdgcn_s_setprio(0);
    asm volatile("s_waitcnt lgkmcnt(0)" ::: "memory");
    __builtin_amdgcn_sched_barrier(0);
    __builtin_amdgcn_s_setprio(1);
#pragma unroll
    for (int nf = 0; nf < 4; nf++)
#pragma unroll
      for (int q = 0; q < 4; q++)
        acc[4 + q][nf] = __builtin_amdgcn_mfma_f32_16x16x32_bf16(afB[q], bf[nf], acc[4 + q][nf], 0, 0, 0);
    __builtin_amdgcn_s_setprio(0);
    if (t + 1 < NT) {
      if (has) asm volatile("s_waitcnt vmcnt(4)" ::: "memory");  // tile t+1 landed
      else     asm volatile("s_waitcnt vmcnt(0)" ::: "memory");
      asm volatile("s_barrier" ::: "memory");  // visibility + restage safety
    }
  }
#undef STG
}

// ---------------- GEMM1 + fused 7-tap conv epilogue: writes dwT directly ----------------
__global__ __launch_bounds__(512, 2) void k_gemm1(const __hip_bfloat16* __restrict__ xbT,
                                                  const __hip_bfloat16* __restrict__ w1b,
                                                  const float* __restrict__ b1,
                                                  const float* __restrict__ weff,
                                                  const float* __restrict__ beff,
                                                  __hip_bfloat16* __restrict__ dwT) {
  __shared__ __hip_bfloat16 As[3 * 256 * 32];
  __shared__ __hip_bfloat16 Bs[3 * 256 * 32];
  // bijective XCD swizzle for nwg=196 (q=24, r=4): o-tile fastest within XCD
  int xcd = blockIdx.x & 7, i = blockIdx.x >> 3;
  int id = (xcd < 4 ? xcd * 25 : 100 + (xcd - 4) * 24) + i;
  int rt = id >> 1, ot = id & 1;
  int n0 = rt * 256, o0 = ot * 256;
  f32x4 acc[8][4];
#pragma unroll
  for (int a = 0; a < 8; a++)
#pragma unroll
    for (int c = 0; c < 4; c++) acc[a][c] = (f32x4){0.f, 0.f, 0.f, 0.f};
  gemm_core32<1024>(xbT + (size_t)n0 * CIN, w1b + (size_t)o0 * CIN, As, Bs, acc);

  int tid = threadIdx.x, lane = tid & 63, w = tid >> 6;
  int wm = w >> 2, wn = w & 3, ln = lane & 15, lm = lane >> 4;
  bool hiT = (lm & 1);
#pragma unroll
  for (int nf = 0; nf < 4; nf++) {
    int o = o0 + wn * 64 + nf * 16 + ln;
    float e[7];
#pragma unroll
    for (int u = 0; u < 7; u++) e[u] = weff[o * 8 + u];
    float be = beff[o];
    float bo = b1[o];
#pragma unroll
    for (int mf = 0; mf < 8; mf++) {
      float av[4], pv[4];
#pragma unroll
      for (int j = 0; j < 4; j++) av[j] = acc[mf][nf][j] + bo;
#pragma unroll
      for (int j = 0; j < 4; j++) pv[j] = __shfl_xor(av[j], 16, 64);
      float ov[4];
      if (hiT) {
#pragma unroll
        for (int j = 0; j < 4; j++) {
          float s = be;
#pragma unroll
          for (int u = 0; u < 7; u++) {
            int ss = 4 + j + u - 3;
            if (ss >= 0 && ss < 8) s += e[u] * (ss < 4 ? pv[ss] : av[ss - 4]);
          }
          ov[j] = s;
        }
      } else {
#pragma unroll
        for (int j = 0; j < 4; j++) {
          float s = be;
#pragma unroll
          for (int u = 0; u < 7; u++) {
            int ss = j + u - 3;
            if (ss >= 0 && ss < 8) s += e[u] * (ss < 4 ? av[ss] : pv[ss - 4]);
          }
          ov[j] = s;
        }
      }
      // row = n0 + mf*32 + wm*16 + lm*4 + j; group start (mult of 8):
      int grow = n0 + mf * 32 + wm * 16 + ((lm >> 1) & 1) * 8;
      int gidx = grow >> 3;  // = b*196 + hw
      int gb = gidx / HWS, ghw = gidx - gb * HWS;
      int tb = hiT ? 4 : 0;
#pragma unroll
      for (int j = 0; j < 4; j++) {
        size_t rr = (size_t)gb * NPB + (size_t)(tb + j) * HWS + ghw;
        dwT[rr * ICH + o] = __float2bfloat16(ov[j]);
      }
    }
  }
}

// ---------------- GEMM2: out = w2b . dwT + b2 + residual; bounced float4 epilogue ----------------
__global__ __launch_bounds__(512, 2) void k_gemm2(const __hip_bfloat16* __restrict__ dwT,
                                                  const __hip_bfloat16* __restrict__ w2b,
                                                  const float* __restrict__ b2,
                                                  const float* __restrict__ xres,
                                                  float* __restrict__ out) {
  __shared__ __align__(16) char smem[98304];
  __hip_bfloat16* As = (__hip_bfloat16*)smem;            // 3*8192 elems = 49152 B
  __hip_bfloat16* Bs = (__hip_bfloat16*)(smem + 49152);
  // 392 blocks = 8 x 49; m-tile fastest within XCD (shares dwT n-panel)
  int id = (blockIdx.x & 7) * 49 + (blockIdx.x >> 3);
  int nt = id >> 2, mt = id & 3;
  int n0 = nt * 256, m0 = mt * 256;
  f32x4 acc[8][4];
#pragma unroll
  for (int a = 0; a < 8; a++)
#pragma unroll
    for (int c = 0; c < 4; c++) acc[a][c] = (f32x4){0.f, 0.f, 0.f, 0.f};
  gemm_core32<512>(w2b + (size_t)m0 * ICH, dwT + (size_t)n0 * ICH, As, Bs, acc);

  int tid = threadIdx.x, lane = tid & 63, w = tid >> 6;
  int wm = w >> 2, wn = w & 3, ln = lane & 15, lm = lane >> 4;
  float* arr = (float*)smem;  // bounce: [64 o2-rows][260 cols] fp32 per pass (66560 B)
  int fc = tid & 63, fr = tid >> 6;  // fr wave-uniform
  int n2 = n0 + fc * 4;
  int bb = n2 / NPB, r = n2 - bb * NPB;
  int t2 = r / HWS, hw = r - t2 * HWS;
  size_t base4 = ((size_t)((bb * TT + t2) * CIN)) * HWS + hw;
#pragma unroll
  for (int p = 0; p < 4; p++) {
    __syncthreads();
    // o2 row = m0 + mf*32 + wm*16 + lm*4 + j; pass p covers mf = 2p, 2p+1
#pragma unroll
    for (int q2 = 0; q2 < 2; q2++) {
      int mf = p * 2 + q2;
#pragma unroll
      for (int nf = 0; nf < 4; nf++)
#pragma unroll
        for (int j = 0; j < 4; j++)
          arr[(q2 * 32 + wm * 16 + lm * 4 + j) * 260 + wn * 64 + nf * 16 + ln] = acc[mf][nf][j];
    }
    __syncthreads();
#pragma unroll
    for (int it = 0; it < 8; it++) {
      int o2l = it * 8 + fr;
      f32x4 v = *(const f32x4*)&arr[o2l * 260 + fc * 4];
      int o2 = m0 + p * 64 + o2l;
      float bo = b2[o2];
      size_t a = base4 + (size_t)o2 * HWS;
      float4 xr = *(const float4*)(xres + a);
      float4 ov = make_float4(v[0] + bo + xr.x, v[1] + bo + xr.y,
                              v[2] + bo + xr.z, v[3] + bo + xr.w);
      *(float4*)(out + a) = ov;
    }
  }
}

extern "C" void kernel_launch(void* const* d_in, const int* in_sizes, int n_in,
                              void* d_out, int out_size, void* d_ws, size_t ws_size,
                              hipStream_t stream) {
  const float* x   = (const float*)d_in[0];
  const float* w1  = (const float*)d_in[1];
  const float* b1  = (const float*)d_in[2];
  const float* wb1 = (const float*)d_in[3];
  const float* bb1 = (const float*)d_in[4];
  const float* wb2 = (const float*)d_in[5];
  const float* bb2 = (const float*)d_in[6];
  const float* wb3 = (const float*)d_in[7];
  const float* bb3 = (const float*)d_in[8];
  const float* wb4 = (const float*)d_in[9];
  const float* bb4 = (const float*)d_in[10];
  const float* w2  = (const float*)d_in[11];
  const float* b2  = (const float*)d_in[12];
  float* out = (float*)d_out;

  // d_out as scratch: xbT bf16 [NF][CIN] at offset 0 (51.4MB; dead before gemm2 writes out)
  __hip_bfloat16* xbT = (__hip_bfloat16*)d_out;

  // ws: dwT 25.69MB + w1b 1MB + w2b 1MB + weff 16KB + beff 2KB
  char* ws = (char*)d_ws;
  __hip_bfloat16* dwT = (__hip_bfloat16*)ws;
  __hip_bfloat16* w1b = (__hip_bfloat16*)(ws + 25690112);
  __hip_bfloat16* w2b = (__hip_bfloat16*)(ws + 25690112 + 1048576);
  float* weff = (float*)(ws + 25690112 + 2097152);
  float* beff = weff + 4096;

  k_prep<<<CB * TT * 16 * 4 + (CIN * ICH + 255) / 256, 256, 0, stream>>>(
      x, xbT, w1, w2, wb1, bb1, wb2, bb2, wb3, bb3, wb4, bb4, w1b, w2b, weff, beff);
  k_gemm1<<<196, 512, 0, stream>>>(xbT, w1b, b1, weff, beff, dwT);
  k_gemm2<<<392, 512, 0, stream>>>(dwT, w2b, b2, x, out);
}

// Round 12
// 123.206 us; speedup vs baseline: 1.0672x; 1.0672x over previous
//
#include <hip/hip_runtime.h>
#include <hip/hip_bf16.h>

typedef short short8 __attribute__((ext_vector_type(8)));
typedef float f32x4 __attribute__((ext_vector_type(4)));
typedef unsigned int uint;

#define CB   16
#define TT   8
#define CIN  1024
#define ICH  512
#define HWS  196
#define NPB  1568   // cols per batch (196*8)
#define NF   25088  // flat cols = 16*1568

static __device__ __forceinline__ unsigned short f2bf(float f) {
  __hip_bfloat16 h = __float2bfloat16(f); unsigned short u; __builtin_memcpy(&u, &h, 2); return u;
}

// async global->LDS, 16B per lane; LDS dest is wave-uniform base + lane*16
static __device__ __forceinline__ void stage16(const void* g, void* l) {
  __builtin_amdgcn_global_load_lds(
      (const __attribute__((address_space(1))) unsigned int*)(unsigned long long)g,
      (__attribute__((address_space(3))) unsigned int*)(unsigned int)(unsigned long long)l,
      16, 0, 0);
}

// ---------------- fused prep: x-transpose blocks [0,8192) + weight blocks ----------------
__global__ void k_prep(const float* __restrict__ x, __hip_bfloat16* __restrict__ xbT,
    const float* __restrict__ w1, const float* __restrict__ w2,
    const float* __restrict__ wb1, const float* __restrict__ bb1,
    const float* __restrict__ wb2, const float* __restrict__ bb2,
    const float* __restrict__ wb3, const float* __restrict__ bb3,
    const float* __restrict__ wb4, const float* __restrict__ bb4,
    __hip_bfloat16* __restrict__ w1b, __hip_bfloat16* __restrict__ w2b,
    float* __restrict__ weff, float* __restrict__ beff) {
  int bid = blockIdx.x;
  if (bid >= CB * TT * 16 * 4) {
    int idx = (bid - CB * TT * 16 * 4) * 256 + threadIdx.x;
    if (idx < CIN * ICH) {
      w1b[idx] = __float2bfloat16(w1[idx]);
      w2b[idx] = __float2bfloat16(w2[idx]);
    }
    if (idx < ICH) {
      float e[7];
#pragma unroll
      for (int u = 0; u < 7; u++) e[u] = wb4[idx * 7 + u];
#pragma unroll
      for (int u = 0; u < 5; u++) e[u + 1] += wb3[idx * 5 + u];
#pragma unroll
      for (int u = 0; u < 3; u++) e[u + 2] += wb2[idx * 3 + u];
      e[3] += wb1[idx];
#pragma unroll
      for (int u = 0; u < 7; u++) weff[idx * 8 + u] = e[u];
      weff[idx * 8 + 7] = 0.f;
      beff[idx] = bb1[idx] + bb2[idx] + bb3[idx] + bb4[idx];
    }
    return;
  }
  __shared__ float tile[64][51];
  int ht = bid & 3;
  int ct = (bid >> 2) & 15;
  int t  = (bid >> 6) & 7;
  int b  = bid >> 9;
  int c0 = ct * 64, h0 = ht * 49;
  const float* src = x + ((size_t)((b * TT + t) * CIN + c0)) * HWS + h0;
  for (int idx = threadIdx.x; idx < 64 * 49; idx += 256) {
    int r = idx / 49, q = idx - r * 49;
    tile[r][q] = src[(size_t)r * HWS + q];
  }
  __syncthreads();
  for (int idx = threadIdx.x; idx < 49 * 16; idx += 256) {
    int h = idx >> 4, g = idx & 15;
    ushort4 pk;
    pk.x = f2bf(tile[g * 4 + 0][h]);
    pk.y = f2bf(tile[g * 4 + 1][h]);
    pk.z = f2bf(tile[g * 4 + 2][h]);
    pk.w = f2bf(tile[g * 4 + 3][h]);
    size_t n1 = (size_t)(h0 + h) * TT + t;
    *(ushort4*)&xbT[((size_t)b * NPB + n1) * CIN + (c0 + g * 4)] = pk;
  }
}

// ---------------- 256x256 GEMM core, BK=64, 16 waves (4x4), 64x64 per wave ----------------
// acc[4][4] = 64 regs/thread -> 4 waves/SIMD (16 waves/CU): 2x the TLP of the 8-wave core.
// A-frag mf -> rows mf*64 + wm*16 + ln  (mf 0,1 in Ah0; mf 2,3 in Ah1 for EVERY wave).
// Staging per tile: 4 loads/thread (Bh0, Bh1, Ah0, Ah1; each half = 1024 lanes x 16B).
// R8's proven 4-phase counted-vmcnt schedule, loads/phase = 1:
//   p0: stage Bh0(t+1); vmcnt(2) [drains Bh0,Bh1,Ah0 of t; leaves Ah1(t)+Bh0(t+1)];
//       barrier; mf0,1 x ck0 (bfA)
//   p1: stage Bh1(t+1); mf0,1 x ck1 (bfB)
//   p2: stage Ah0(t+1); vmcnt(3) [drains Ah1(t)]; barrier; mf2,3 x ck0 (reuse bfA)
//   p3: stage Ah1(t+1); reads; lgkm(0); END barrier (restage safety); mf2,3 x ck1 (bfB)
// Tails (no stage): p0 vmcnt(1), p2 vmcnt(0).
// Swizzle: 8 chunks of 16B per 128B row; LDS slot s of row r holds chunk s^(r&7);
// stage source pre-swizzled (schk), reads use ck0/ck1 involution (row&7 == ln&7).
template <int KD>
static __device__ __forceinline__ void gemm_core16(
    const __hip_bfloat16* __restrict__ Ar,  // 256 rows x KD (k-contiguous)
    const __hip_bfloat16* __restrict__ Br,  // 256 rows x KD
    __hip_bfloat16* As, __hip_bfloat16* Bs, f32x4 (&acc)[4][4]) {
  constexpr int NT = KD / 64;
  const int tid = threadIdx.x;
  const int lane = tid & 63, w = tid >> 6;   // w 0..15
  const int wm = w >> 2, wn = w & 3;
  const int ln = lane & 15, lm = lane >> 4;
  // staging: half h -> rows h*128 + w*8 + (lane>>3); chunk lane&7 pre-swizzled
  const int srow = lane >> 3;                 // 0..7 (== row&7)
  const int schk = (lane & 7) ^ srow;
  const __hip_bfloat16* aS = Ar + (size_t)(w * 8 + srow) * KD + schk * 8;
  const __hip_bfloat16* bS = Br + (size_t)(w * 8 + srow) * KD + schk * 8;
  __hip_bfloat16* aD = As + (w * 8) * 64;
  __hip_bfloat16* bD = Bs + (w * 8) * 64;
  const int ck0 = ((lm) ^ (ln & 7)) * 8;
  const int ck1 = ((4 + lm) ^ (ln & 7)) * 8;
  const int rab = (wm * 16 + ln) * 64;  // + mf*4096 (64 rows x 64 elems)
  const int rbb = (wn * 64 + ln) * 64;  // + nf*1024 (16 rows x 64 elems)

#define STG(src, dst, h, kt, buf) \
  stage16(src + (size_t)((h) * 128) * KD + (kt) * 64, dst + (buf) * 16384 + ((h) * 128) * 64)

  // prologue: tile 0 -> buf 0 (order Bh0, Bh1, Ah0, Ah1)
  STG(bS, bD, 0, 0, 0); STG(bS, bD, 1, 0, 0);
  STG(aS, aD, 0, 0, 0); STG(aS, aD, 1, 0, 0);

  short8 af0, af1, bfA[4], bfB[4];
  for (int t = 0; t < NT; t++) {
    const int buf = t & 1, nb = buf ^ 1;
    const bool has = (t + 1 < NT);
    const __hip_bfloat16* Ab = As + buf * 16384;
    const __hip_bfloat16* Bb = Bs + buf * 16384;
    // ---- p0: mf0,1 x ck0 ----
    if (has) STG(bS, bD, 0, t + 1, nb);
    if (has) asm volatile("s_waitcnt vmcnt(2)" ::: "memory");
    else     asm volatile("s_waitcnt vmcnt(1)" ::: "memory");
    asm volatile("s_barrier" ::: "memory");  // B(t) + Ah0(t) visible to all waves
    af0 = *(const short8*)&Ab[rab + ck0];
    af1 = *(const short8*)&Ab[rab + 4096 + ck0];
#pragma unroll
    for (int nf = 0; nf < 4; nf++) bfA[nf] = *(const short8*)&Bb[rbb + nf * 1024 + ck0];
    asm volatile("s_waitcnt lgkmcnt(0)" ::: "memory");
    __builtin_amdgcn_sched_barrier(0);
    __builtin_amdgcn_s_setprio(1);
#pragma unroll
    for (int nf = 0; nf < 4; nf++) {
      acc[0][nf] = __builtin_amdgcn_mfma_f32_16x16x32_bf16(af0, bfA[nf], acc[0][nf], 0, 0, 0);
      acc[1][nf] = __builtin_amdgcn_mfma_f32_16x16x32_bf16(af1, bfA[nf], acc[1][nf], 0, 0, 0);
    }
    __builtin_amdgcn_s_setprio(0);
    // ---- p1: mf0,1 x ck1 ----
    if (has) STG(bS, bD, 1, t + 1, nb);
    af0 = *(const short8*)&Ab[rab + ck1];
    af1 = *(const short8*)&Ab[rab + 4096 + ck1];
#pragma unroll
    for (int nf = 0; nf < 4; nf++) bfB[nf] = *(const short8*)&Bb[rbb + nf * 1024 + ck1];
    asm volatile("s_waitcnt lgkmcnt(0)" ::: "memory");
    __builtin_amdgcn_sched_barrier(0);
    __builtin_amdgcn_s_setprio(1);
#pragma unroll
    for (int nf = 0; nf < 4; nf++) {
      acc[0][nf] = __builtin_amdgcn_mfma_f32_16x16x32_bf16(af0, bfB[nf], acc[0][nf], 0, 0, 0);
      acc[1][nf] = __builtin_amdgcn_mfma_f32_16x16x32_bf16(af1, bfB[nf], acc[1][nf], 0, 0, 0);
    }
    __builtin_amdgcn_s_setprio(0);
    // ---- p2: mf2,3 x ck0 ----
    if (has) STG(aS, aD, 0, t + 1, nb);
    if (has) asm volatile("s_waitcnt vmcnt(3)" ::: "memory");
    else     asm volatile("s_waitcnt vmcnt(0)" ::: "memory");
    asm volatile("s_barrier" ::: "memory");  // Ah1(t) visible
    af0 = *(const short8*)&Ab[rab + 2 * 4096 + ck0];
    af1 = *(const short8*)&Ab[rab + 3 * 4096 + ck0];
    asm volatile("s_waitcnt lgkmcnt(0)" ::: "memory");
    __builtin_amdgcn_sched_barrier(0);
    __builtin_amdgcn_s_setprio(1);
#pragma unroll
    for (int nf = 0; nf < 4; nf++) {
      acc[2][nf] = __builtin_amdgcn_mfma_f32_16x16x32_bf16(af0, bfA[nf], acc[2][nf], 0, 0, 0);
      acc[3][nf] = __builtin_amdgcn_mfma_f32_16x16x32_bf16(af1, bfA[nf], acc[3][nf], 0, 0, 0);
    }
    __builtin_amdgcn_s_setprio(0);
    // ---- p3: mf2,3 x ck1; end barrier before MFMAs (overlap others' staging) ----
    if (has) STG(aS, aD, 1, t + 1, nb);
    af0 = *(const short8*)&Ab[rab + 2 * 4096 + ck1];
    af1 = *(const short8*)&Ab[rab + 3 * 4096 + ck1];
    asm volatile("s_waitcnt lgkmcnt(0)" ::: "memory");
    __builtin_amdgcn_sched_barrier(0);
    asm volatile("s_barrier" ::: "memory");  // all reads of buf t done -> restage safe
    __builtin_amdgcn_s_setprio(1);
#pragma unroll
    for (int nf = 0; nf < 4; nf++) {
      acc[2][nf] = __builtin_amdgcn_mfma_f32_16x16x32_bf16(af0, bfB[nf], acc[2][nf], 0, 0, 0);
      acc[3][nf] = __builtin_amdgcn_mfma_f32_16x16x32_bf16(af1, bfB[nf], acc[3][nf], 0, 0, 0);
    }
    __builtin_amdgcn_s_setprio(0);
  }
#undef STG
}

// ---------------- GEMM1 + fused 7-tap conv epilogue: writes dwT directly ----------------
__global__ __launch_bounds__(1024, 4) void k_gemm1(const __hip_bfloat16* __restrict__ xbT,
                                                   const __hip_bfloat16* __restrict__ w1b,
                                                   const float* __restrict__ b1,
                                                   const float* __restrict__ weff,
                                                   const float* __restrict__ beff,
                                                   __hip_bfloat16* __restrict__ dwT) {
  __shared__ __hip_bfloat16 As[2 * 256 * 64];
  __shared__ __hip_bfloat16 Bs[2 * 256 * 64];
  // bijective XCD swizzle for nwg=196 (q=24, r=4): o-tile fastest within XCD
  int xcd = blockIdx.x & 7, i = blockIdx.x >> 3;
  int id = (xcd < 4 ? xcd * 25 : 100 + (xcd - 4) * 24) + i;
  int rt = id >> 1, ot = id & 1;
  int n0 = rt * 256, o0 = ot * 256;
  f32x4 acc[4][4];
#pragma unroll
  for (int a = 0; a < 4; a++)
#pragma unroll
    for (int c = 0; c < 4; c++) acc[a][c] = (f32x4){0.f, 0.f, 0.f, 0.f};
  gemm_core16<1024>(xbT + (size_t)n0 * CIN, w1b + (size_t)o0 * CIN, As, Bs, acc);

  int tid = threadIdx.x, lane = tid & 63, w = tid >> 6;
  int wm = w >> 2, wn = w & 3, ln = lane & 15, lm = lane >> 4;
  bool hiT = (lm & 1);
#pragma unroll
  for (int nf = 0; nf < 4; nf++) {
    int o = o0 + wn * 64 + nf * 16 + ln;
    float e[7];
#pragma unroll
    for (int u = 0; u < 7; u++) e[u] = weff[o * 8 + u];
    float be = beff[o];
    float bo = b1[o];
#pragma unroll
    for (int mf = 0; mf < 4; mf++) {
      float av[4], pv[4];
#pragma unroll
      for (int j = 0; j < 4; j++) av[j] = acc[mf][nf][j] + bo;
#pragma unroll
      for (int j = 0; j < 4; j++) pv[j] = __shfl_xor(av[j], 16, 64);
      float ov[4];
      if (hiT) {
#pragma unroll
        for (int j = 0; j < 4; j++) {
          float s = be;
#pragma unroll
          for (int u = 0; u < 7; u++) {
            int ss = 4 + j + u - 3;
            if (ss >= 0 && ss < 8) s += e[u] * (ss < 4 ? pv[ss] : av[ss - 4]);
          }
          ov[j] = s;
        }
      } else {
#pragma unroll
        for (int j = 0; j < 4; j++) {
          float s = be;
#pragma unroll
          for (int u = 0; u < 7; u++) {
            int ss = j + u - 3;
            if (ss >= 0 && ss < 8) s += e[u] * (ss < 4 ? av[ss] : pv[ss - 4]);
          }
          ov[j] = s;
        }
      }
      // row = n0 + mf*64 + wm*16 + lm*4 + j; group start (mult of 8):
      int grow = n0 + mf * 64 + wm * 16 + ((lm >> 1) & 1) * 8;
      int gidx = grow >> 3;  // = b*196 + hw
      int gb = gidx / HWS, ghw = gidx - gb * HWS;
      int tb = hiT ? 4 : 0;
#pragma unroll
      for (int j = 0; j < 4; j++) {
        size_t rr = (size_t)gb * NPB + (size_t)(tb + j) * HWS + ghw;
        dwT[rr * ICH + o] = __float2bfloat16(ov[j]);
      }
    }
  }
}

// ---------------- GEMM2: out = w2b . dwT + b2 + residual; bounced float4 epilogue ----------------
__global__ __launch_bounds__(1024, 4) void k_gemm2(const __hip_bfloat16* __restrict__ dwT,
                                                   const __hip_bfloat16* __restrict__ w2b,
                                                   const float* __restrict__ b2,
                                                   const float* __restrict__ xres,
                                                   float* __restrict__ out) {
  __shared__ __align__(16) char smem[131072];
  __hip_bfloat16* As = (__hip_bfloat16*)smem;
  __hip_bfloat16* Bs = (__hip_bfloat16*)(smem + 65536);
  // 392 blocks = 8 x 49; m-tile fastest within XCD (shares dwT n-panel)
  int id = (blockIdx.x & 7) * 49 + (blockIdx.x >> 3);
  int nt = id >> 2, mt = id & 3;
  int n0 = nt * 256, m0 = mt * 256;
  f32x4 acc[4][4];
#pragma unroll
  for (int a = 0; a < 4; a++)
#pragma unroll
    for (int c = 0; c < 4; c++) acc[a][c] = (f32x4){0.f, 0.f, 0.f, 0.f};
  gemm_core16<512>(w2b + (size_t)m0 * ICH, dwT + (size_t)n0 * ICH, As, Bs, acc);

  int tid = threadIdx.x, lane = tid & 63, w = tid >> 6;
  int wm = w >> 2, wn = w & 3, ln = lane & 15, lm = lane >> 4;
  float* arr = (float*)smem;  // bounce: [64 o2-rows][260 cols] fp32 per pass (66560 B)
  int fc = tid & 63, fr = tid >> 6;  // fr 0..15, wave-uniform
  int n2 = n0 + fc * 4;
  int bb = n2 / NPB, r = n2 - bb * NPB;
  int t2 = r / HWS, hw = r - t2 * HWS;
  size_t base4 = ((size_t)((bb * TT + t2) * CIN)) * HWS + hw;
#pragma unroll
  for (int p = 0; p < 4; p++) {
    __syncthreads();
    // o2 row = m0 + mf*64 + wm*16 + lm*4 + j; pass p covers mf = p (rows p*64..p*64+63)
#pragma unroll
    for (int nf = 0; nf < 4; nf++)
#pragma unroll
      for (int j = 0; j < 4; j++)
        arr[(wm * 16 + lm * 4 + j) * 260 + wn * 64 + nf * 16 + ln] = acc[p][nf][j];
    __syncthreads();
#pragma unroll
    for (int it = 0; it < 4; it++) {
      int o2l = it * 16 + fr;
      f32x4 v = *(const f32x4*)&arr[o2l * 260 + fc * 4];
      int o2 = m0 + p * 64 + o2l;
      float bo = b2[o2];
      size_t a = base4 + (size_t)o2 * HWS;
      float4 xr = *(const float4*)(xres + a);
      float4 ov = make_float4(v[0] + bo + xr.x, v[1] + bo + xr.y,
                              v[2] + bo + xr.z, v[3] + bo + xr.w);
      *(float4*)(out + a) = ov;
    }
  }
}

extern "C" void kernel_launch(void* const* d_in, const int* in_sizes, int n_in,
                              void* d_out, int out_size, void* d_ws, size_t ws_size,
                              hipStream_t stream) {
  const float* x   = (const float*)d_in[0];
  const float* w1  = (const float*)d_in[1];
  const float* b1  = (const float*)d_in[2];
  const float* wb1 = (const float*)d_in[3];
  const float* bb1 = (const float*)d_in[4];
  const float* wb2 = (const float*)d_in[5];
  const float* bb2 = (const float*)d_in[6];
  const float* wb3 = (const float*)d_in[7];
  const float* bb3 = (const float*)d_in[8];
  const float* wb4 = (const float*)d_in[9];
  const float* bb4 = (const float*)d_in[10];
  const float* w2  = (const float*)d_in[11];
  const float* b2  = (const float*)d_in[12];
  float* out = (float*)d_out;

  // d_out as scratch: xbT bf16 [NF][CIN] at offset 0 (51.4MB; dead before gemm2 writes out)
  __hip_bfloat16* xbT = (__hip_bfloat16*)d_out;

  // ws: dwT 25.69MB + w1b 1MB + w2b 1MB + weff 16KB + beff 2KB
  char* ws = (char*)d_ws;
  __hip_bfloat16* dwT = (__hip_bfloat16*)ws;
  __hip_bfloat16* w1b = (__hip_bfloat16*)(ws + 25690112);
  __hip_bfloat16* w2b = (__hip_bfloat16*)(ws + 25690112 + 1048576);
  float* weff = (float*)(ws + 25690112 + 2097152);
  float* beff = weff + 4096;

  k_prep<<<CB * TT * 16 * 4 + (CIN * ICH + 255) / 256, 256, 0, stream>>>(
      x, xbT, w1, w2, wb1, bb1, wb2, bb2, wb3, bb3, wb4, bb4, w1b, w2b, weff, beff);
  k_gemm1<<<196, 1024, 0, stream>>>(xbT, w1b, b1, weff, beff, dwT);
  k_gemm2<<<392, 1024, 0, stream>>>(dwT, w2b, b2, x, out);
}